// Round 4
// baseline (216.896 us; speedup 1.0000x reference)
//
#include <hip/hip_runtime.h>

// SpecialFlatten: out_f2[b][i][j] = in_f2[b][j][i], where f2 = adjacent float pair.
// B=32, R=2048, C=512 (C2=256 float2 columns). Batched 2048x256 float2 transpose.
// Pure streaming permutation: 128 MiB read + 128 MiB write, zero reuse.

#define TILE 64   // tile edge in float2 elements

// Native clang vector types: required by __builtin_nontemporal_load/store,
// and support .xy/.zw swizzles.
typedef float fx4 __attribute__((ext_vector_type(4)));
typedef float fx2 __attribute__((ext_vector_type(2)));

__global__ __launch_bounds__(256) void transpose_pair_kernel(
    const float* __restrict__ x, float* __restrict__ y, int R, int C2) {
    // Transposed-store LDS tile: sT[pcol][row] as float2 elements.
    // Row stride 66 f2 = 528 B = 33*16 -> every sT[c][2tx] is 16B-aligned,
    // so the store-side gather is ONE ds_read_b128 per float4 (was 4x b32).
    // Read phase: min bank cost; write phase: 2x min (acceptable, LDS ~16% util).
    __shared__ __align__(16) fx2 sT[TILE][TILE + 2];

    const int tx = threadIdx.x;   // 0..31
    const int ty = threadIdx.y;   // 0..7

    const int c0 = blockIdx.x * TILE;   // pair-column tile origin
    const int j0 = blockIdx.y * TILE;   // row tile origin
    const int b  = blockIdx.z;

    const size_t base_f = (size_t)b * R * (size_t)(C2 * 2);  // floats

    // ---- Load phase: issue all 8 16B nontemporal loads (8 outstanding vmem),
    // then drain into LDS already transposed.
    const fx4* inp = (const fx4*)(x + base_f);
    const int row_f4 = C2 / 2;           // float4s per input row
    fx4 v[8];
    #pragma unroll
    for (int k = 0; k < 8; ++k) {
        const int j = j0 + ty + 8 * k;
        v[k] = __builtin_nontemporal_load(&inp[(size_t)j * row_f4 + (c0 >> 1) + tx]);
    }
    #pragma unroll
    for (int k = 0; k < 8; ++k) {
        const int jl = ty + 8 * k;       // 0..63
        sT[2 * tx    ][jl] = v[k].xy;    // IN_f2[j][c0+2tx]
        sT[2 * tx + 1][jl] = v[k].zw;    // IN_f2[j][c0+2tx+1]
    }
    __syncthreads();

    // ---- Store phase: one b128 LDS read per output float4, then 8
    // back-to-back 16B nontemporal stores.
    float* yb = y + base_f;
    const int orow_f4 = R / 2;           // float4s per output row
    fx4 w[8];
    #pragma unroll
    for (int k = 0; k < 8; ++k) {
        const int cl = ty + 8 * k;       // 0..63
        w[k] = *(const fx4*)&sT[cl][2 * tx];   // {OUT_f2[c][j0+2tx], OUT_f2[c][j0+2tx+1]}
    }
    #pragma unroll
    for (int k = 0; k < 8; ++k) {
        const int c = c0 + ty + 8 * k;
        __builtin_nontemporal_store(w[k], (fx4*)yb + (size_t)c * orow_f4 + (j0 >> 1) + tx);
    }
}

extern "C" void kernel_launch(void* const* d_in, const int* in_sizes, int n_in,
                              void* d_out, int out_size, void* d_ws, size_t ws_size,
                              hipStream_t stream) {
    const float* x = (const float*)d_in[0];
    float* y = (float*)d_out;

    const int B = 32, R = 2048, C = 512;
    const int C2 = C / 2;  // 256 float2 columns

    dim3 block(32, 8, 1);
    dim3 grid(C2 / TILE, R / TILE, B);  // (4, 32, 32)
    transpose_pair_kernel<<<grid, block, 0, stream>>>(x, y, R, C2);
}